// Round 3
// baseline (772.236 us; speedup 1.0000x reference)
//
#include <hip/hip_runtime.h>
#include <math.h>

// Problem constants
#define HH 180
#define WDIM 360
#define CDIM 512
#define NP 64800           // 180*360 positions
#define PL 184320          // 360*512 per-h plane (also idht norm)

typedef unsigned short u16;
typedef __attribute__((ext_vector_type(8))) short short8;  // 8 bf16 = 4 VGPR
typedef __attribute__((ext_vector_type(4))) float f4;      // 4 fp32 acc

__device__ __forceinline__ u16 f2bf(float f){
    unsigned u = __float_as_uint(f);
    return (u16)((u + 0x7fffu + ((u >> 16) & 1u)) >> 16);   // RNE
}
__device__ __forceinline__ void gl_lds16(const void* g, void* l){
    __builtin_amdgcn_global_load_lds((const __attribute__((address_space(1))) void*)g,
                                     (__attribute__((address_space(3))) void*)l, 16, 0, 0);
}

// ---------------- prep: cas matrices (bf16) + folded transposed weights ----------------
__global__ void prep(const float* __restrict__ w1, const float* __restrict__ w2,
                     u16* __restrict__ casC, u16* __restrict__ casW, u16* __restrict__ wts)
{
    int idx = blockIdx.x * 256 + threadIdx.x;
    if (idx < 512*512){
        int i = idx >> 9, j = idx & 511;
        int m = (i * j) & 511;                       // exact angle reduction
        float a = (float)m * (6.283185307179586f / 512.0f);
        float s, c; __sincosf(a, &s, &c);
        casC[idx] = f2bf(c + s);
    }
    if (idx < 360*384){
        int i = idx / 384, j = idx - (idx / 384) * 384;
        u16 v = 0;
        if (j < 360){
            int m = (i * j) % 360;
            float a = (float)m * (6.283185307179586f / 360.0f);
            float s, c; __sincosf(a, &s, &c);
            v = f2bf(c + s);
        }
        casW[idx] = v;
    }
    if (idx < 131072){
        int s = idx >> 15, r = idx & 32767;
        int kb = r >> 12, o = (r >> 6) & 63, ii = r & 63;
        const float* w = (s < 2) ? w1 : w2;
        float v0 = w[kb*4096 + ii*64 + o];
        float v1 = w[32768 + kb*4096 + ii*64 + o];
        float v = 0.5f * ((s & 1) ? (v0 - v1) : (v0 + v1));
        wts[idx] = f2bf(v);
    }
}

// ---------------- x (fp32) -> bf16, RNE (same rounding the old reg-staging did) ----------------
__global__ __launch_bounds__(256)
void cvt_k(const float* __restrict__ x, u16* __restrict__ xb)
{
    long long i = ((long long)blockIdx.x * 256 + threadIdx.x) * 8;
    float4 a = *(const float4*)(x + i);
    float4 b = *(const float4*)(x + i + 4);
    uint4 w;
    w.x = (unsigned)f2bf(a.x) | ((unsigned)f2bf(a.y) << 16);
    w.y = (unsigned)f2bf(a.z) | ((unsigned)f2bf(a.w) << 16);
    w.z = (unsigned)f2bf(b.x) | ((unsigned)f2bf(b.y) << 16);
    w.w = (unsigned)f2bf(b.z) | ((unsigned)f2bf(b.w) << 16);
    *(uint4*)(xb + i) = w;
}

// ---------------- MFMA GEMM: C(Mx512) = A(MxK) * B^T(512xK), bf16 inputs ----------------
// 128x128 tile, 4 waves. 3-deep software pipeline with COUNTED vmcnt (T3/T4):
//   prologue stages tiles 0,1,2 (12 gl_lds in flight per wave);
//   iter kt: s_waitcnt vmcnt(8)  -> own tile-kt loads landed, kt+1/kt+2 still flying
//            s_barrier           -> all waves' tile-kt loads landed
//            ds_read + 16 MFMA from buf[kt%3]
//            s_barrier           -> all waves done READING buf[kt%3]
//            restage tile kt+3 into buf[kt%3]   (clamped to nK-1: no OOB)
// Raw barriers carry no implicit waitcnt; sched_barrier(0) pins loads/MFMA inside
// their region so nothing crosses a barrier (rule #18 analog for raw s_barrier).
// LDS layout per buffer: k-chunk-major [4 chunks][128 rows][8 u16] (conflict-free b128).
// SWAP=1: m204 bijective XCD swizzle on 1-D grid, col-block fastest per XCD chunk.
// STORE=0: bf16 [m][512]. STORE=1: bf16 transposed T[h][d][w]. STORE=2: fp32 +residual.
template<int STORE, int SWAP>
__global__ __launch_bounds__(256)
void gemm_k(const u16* __restrict__ A, int ldA, long long sA, int clampA,
            const u16* __restrict__ B, int ldB, long long sB,
            void* __restrict__ C, long long sC, int Mreal,
            const float* __restrict__ X, float scale, int nK, int nbx)
{
    __shared__ u16 As[3][4096];   // [buf][4 chunks][128 rows][8]
    __shared__ u16 Bs[3][4096];

    const int tid = threadIdx.x, wv = tid >> 6, l = tid & 63;
    const int l16 = l & 15, quad = l >> 4;
    const int z = blockIdx.z;

    int bx, by;
    if constexpr (SWAP){
        int n = gridDim.x;
        int q = n >> 3, r = n & 7;
        int xcd = blockIdx.x & 7, idx = blockIdx.x >> 3;
        int swz = (xcd < r ? xcd*(q+1) : r*(q+1) + (xcd-r)*q) + idx;
        bx = swz / nbx;            // row-block
        by = swz - bx * nbx;       // col-block (fastest within XCD chunk)
    } else {
        bx = blockIdx.x;
        by = blockIdx.y;
    }
    const int row0 = bx * 128, col0 = by * 128;

    // wave w stages row-half rh = w&1, chunks {w>>1, w>>1+2} of each operand
    const int rh = wv & 1, c0 = wv >> 1;

    const u16* gB = B + sB * z + (long long)(col0 + rh*64 + l) * ldB;
    int ar = row0 + rh*64 + l; ar = ar <= clampA ? ar : clampA;
    const u16* gA = A + sA * z + (long long)ar * ldA;

    f4 acc[4][4];
    #pragma unroll
    for (int mt = 0; mt < 4; ++mt)
        #pragma unroll
        for (int nt = 0; nt < 4; ++nt)
            acc[mt][nt] = (f4)0.0f;

    const int mrow = (wv >> 1) * 64, ncol = (wv & 1) * 64;

    #define STAGE(buf, kt) do{ const int k0_ = (kt)*32;                          \
        gl_lds16(gB + k0_ + c0*8,     &Bs[buf][c0*1024     + rh*512]);           \
        gl_lds16(gB + k0_ + (c0+2)*8, &Bs[buf][(c0+2)*1024 + rh*512]);           \
        gl_lds16(gA + k0_ + c0*8,     &As[buf][c0*1024     + rh*512]);           \
        gl_lds16(gA + k0_ + (c0+2)*8, &As[buf][(c0+2)*1024 + rh*512]); }while(0)

    // ---- prologue: 3 tiles in flight (12 vmem ops per wave) ----
    STAGE(0, 0);
    STAGE(1, 1);
    STAGE(2, 2);

    int cur = 0;
    for (int kt = 0; kt < nK; ++kt){
        // own tile-kt loads landed (8 = two tiles x 4 loads still outstanding)
        asm volatile("s_waitcnt vmcnt(8)" ::: "memory");
        __builtin_amdgcn_s_barrier();          // all waves' tile-kt loads landed
        __builtin_amdgcn_sched_barrier(0);

        short8 af[4];
        #pragma unroll
        for (int mt = 0; mt < 4; ++mt)
            af[mt] = *(const short8*)&As[cur][quad*1024 + (mrow + mt*16 + l16)*8];
        #pragma unroll
        for (int nt = 0; nt < 4; ++nt){
            short8 bfv = *(const short8*)&Bs[cur][quad*1024 + (ncol + nt*16 + l16)*8];
            #pragma unroll
            for (int mt = 0; mt < 4; ++mt)
                acc[mt][nt] = __builtin_amdgcn_mfma_f32_16x16x32_bf16(af[mt], bfv, acc[mt][nt], 0, 0, 0);
        }

        __builtin_amdgcn_sched_barrier(0);     // no ds_read may sink past this
        __builtin_amdgcn_s_barrier();          // all waves done reading buf[cur]
        __builtin_amdgcn_sched_barrier(0);     // no stage may hoist above

        int nxt = kt + 3; if (nxt > nK - 1) nxt = nK - 1;   // clamp: no OOB global reads
        STAGE(cur, nxt);
        cur = (cur == 2) ? 0 : cur + 1;
    }
    #undef STAGE

    // epilogue: C/D layout col=lane&15, row=quad*4+reg
    #pragma unroll
    for (int mt = 0; mt < 4; ++mt){
        #pragma unroll
        for (int i = 0; i < 4; ++i){
            int gr = row0 + mrow + mt*16 + quad*4 + i;
            if (gr >= Mreal) continue;
            int th = 0, tw = 0;
            if constexpr (STORE == 1){ th = gr / 360; tw = gr - th * 360; }
            #pragma unroll
            for (int nt = 0; nt < 4; ++nt){
                int gc = col0 + ncol + nt*16 + l16;
                if constexpr (STORE == 0){
                    ((u16*)C)[sC*z + (long long)gr*512 + gc] = f2bf(acc[mt][nt][i]);
                } else if constexpr (STORE == 1){
                    ((u16*)C)[((long long)th*512 + gc)*360 + tw] = f2bf(acc[mt][nt][i]);
                } else {
                    long long off = sC*z + (long long)gr*512 + gc;
                    ((float*)C)[off] = fmaf(acc[mt][nt][i], scale, X[off]);
                }
            }
        }
    }
}

// ---------------- MFMA block-MLP + softshrink ----------------
__global__ __launch_bounds__(256)
void mlp_k(const u16* __restrict__ xh, const u16* __restrict__ wts,
           const float* __restrict__ b1, const float* __restrict__ b2,
           u16* __restrict__ yout)
{
    __shared__ u16 sW0[64*72], sW1[64*72];
    __shared__ u16 sXh[64*72], sXn[64*72], s1k[64*72], s1n[64*72];
    __shared__ float sb[256];

    const int tid = threadIdx.x;
    const int wv = tid >> 6, l = tid & 63, lane16 = l & 15, quad = l >> 4;
    const int kb = blockIdx.y;
    const int p0 = blockIdx.x * 64;
    const int w16 = wv * 16;

    if (tid < 64){
        sb[tid]       = b1[kb*64 + tid];
        sb[64 + tid]  = b1[512 + kb*64 + tid];
        sb[128 + tid] = b2[kb*64 + tid];
        sb[192 + tid] = b2[512 + kb*64 + tid];
    }
    {
        const int r = tid >> 2, sg = (tid & 3) * 16;
        const u16* s0 = wts + kb*4096 + r*64 + sg;            // w1a_t
        const u16* s1 = wts + 32768 + kb*4096 + r*64 + sg;    // w1b_t
        *(uint4*)&sW0[r*72 + sg]     = *(const uint4*)s0;
        *(uint4*)&sW0[r*72 + sg + 8] = *(const uint4*)(s0 + 8);
        *(uint4*)&sW1[r*72 + sg]     = *(const uint4*)s1;
        *(uint4*)&sW1[r*72 + sg + 8] = *(const uint4*)(s1 + 8);

        int p = p0 + r; int pc = p <= 64799 ? p : 64799;
        int h = pc / 360; int v = pc - h * 360;
        int hn = (h == 0) ? 0 : (180 - h);
        int vn = (v == 0) ? 0 : (360 - v);
        long long bh = (long long)pc * 512 + kb*64 + sg;
        long long bn = (long long)(hn*360 + vn) * 512 + kb*64 + sg;
        *(uint4*)&sXh[r*72 + sg]     = *(const uint4*)&xh[bh];
        *(uint4*)&sXh[r*72 + sg + 8] = *(const uint4*)&xh[bh + 8];
        *(uint4*)&sXn[r*72 + sg]     = *(const uint4*)&xh[bn];
        *(uint4*)&sXn[r*72 + sg + 8] = *(const uint4*)&xh[bn + 8];
    }
    __syncthreads();

    // -------- layer 1 --------
    f4 aK[4], aN[4];
    #pragma unroll
    for (int nt = 0; nt < 4; ++nt){ aK[nt] = (f4)0.0f; aN[nt] = (f4)0.0f; }
    #pragma unroll
    for (int kq = 0; kq < 2; ++kq){
        short8 fxh = *(const short8*)&sXh[(w16 + lane16)*72 + kq*32 + quad*8];
        short8 fxn = *(const short8*)&sXn[(w16 + lane16)*72 + kq*32 + quad*8];
        #pragma unroll
        for (int nt = 0; nt < 4; ++nt){
            short8 wa = *(const short8*)&sW0[(nt*16 + lane16)*72 + kq*32 + quad*8];
            short8 wb = *(const short8*)&sW1[(nt*16 + lane16)*72 + kq*32 + quad*8];
            aK[nt] = __builtin_amdgcn_mfma_f32_16x16x32_bf16(fxh, wa, aK[nt], 0,0,0);
            aK[nt] = __builtin_amdgcn_mfma_f32_16x16x32_bf16(fxn, wb, aK[nt], 0,0,0);
            aN[nt] = __builtin_amdgcn_mfma_f32_16x16x32_bf16(fxn, wa, aN[nt], 0,0,0);
            aN[nt] = __builtin_amdgcn_mfma_f32_16x16x32_bf16(fxh, wb, aN[nt], 0,0,0);
        }
    }
    #pragma unroll
    for (int nt = 0; nt < 4; ++nt){
        int cc = nt*16 + lane16;
        #pragma unroll
        for (int i = 0; i < 4; ++i){
            int rr = w16 + quad*4 + i;
            float vk = fmaxf(aK[nt][i] + sb[cc], 0.f);
            float vn = fmaxf(aN[nt][i] + sb[64 + cc], 0.f);
            s1k[rr*72 + cc] = f2bf(vk);
            s1n[rr*72 + cc] = f2bf(vn);
        }
    }
    __syncthreads();

    // -------- swap weights to layer 2 --------
    {
        const int r = tid >> 2, sg = (tid & 3) * 16;
        const u16* s0 = wts + 65536 + kb*4096 + r*64 + sg;    // w2a_t
        const u16* s1 = wts + 98304 + kb*4096 + r*64 + sg;    // w2b_t
        *(uint4*)&sW0[r*72 + sg]     = *(const uint4*)s0;
        *(uint4*)&sW0[r*72 + sg + 8] = *(const uint4*)(s0 + 8);
        *(uint4*)&sW1[r*72 + sg]     = *(const uint4*)s1;
        *(uint4*)&sW1[r*72 + sg + 8] = *(const uint4*)(s1 + 8);
    }
    __syncthreads();

    // -------- layer 2a: o2k --------
    f4 k2[4];
    #pragma unroll
    for (int nt = 0; nt < 4; ++nt) k2[nt] = (f4)0.0f;
    #pragma unroll
    for (int kq = 0; kq < 2; ++kq){
        short8 a1k = *(const short8*)&s1k[(w16 + lane16)*72 + kq*32 + quad*8];
        short8 a1n = *(const short8*)&s1n[(w16 + lane16)*72 + kq*32 + quad*8];
        #pragma unroll
        for (int nt = 0; nt < 4; ++nt){
            short8 wa = *(const short8*)&sW0[(nt*16 + lane16)*72 + kq*32 + quad*8];
            short8 wb = *(const short8*)&sW1[(nt*16 + lane16)*72 + kq*32 + quad*8];
            k2[nt] = __builtin_amdgcn_mfma_f32_16x16x32_bf16(a1k, wa, k2[nt], 0,0,0);
            k2[nt] = __builtin_amdgcn_mfma_f32_16x16x32_bf16(a1n, wb, k2[nt], 0,0,0);
        }
    }
    #pragma unroll
    for (int nt = 0; nt < 4; ++nt){
        int cc = nt*16 + lane16;
        #pragma unroll
        for (int i = 0; i < 4; ++i){
            int rr = w16 + quad*4 + i;
            float v2 = k2[nt][i] + sb[128 + cc];
            k2[nt][i] = v2;                        // keep o2k (with bias) in regs
            sXh[rr*72 + cc] = f2bf(v2);            // reuse sXh as o2k A-operand
        }
    }
    __syncthreads();

    // -------- layer 2b: o2n (consumes o2k per source bug) + softshrink --------
    f4 n2[4];
    #pragma unroll
    for (int nt = 0; nt < 4; ++nt) n2[nt] = (f4)0.0f;
    #pragma unroll
    for (int kq = 0; kq < 2; ++kq){
        short8 a1n = *(const short8*)&s1n[(w16 + lane16)*72 + kq*32 + quad*8];
        short8 a2k = *(const short8*)&sXh[(w16 + lane16)*72 + kq*32 + quad*8];
        #pragma unroll
        for (int nt = 0; nt < 4; ++nt){
            short8 wa = *(const short8*)&sW0[(nt*16 + lane16)*72 + kq*32 + quad*8];
            short8 wb = *(const short8*)&sW1[(nt*16 + lane16)*72 + kq*32 + quad*8];
            n2[nt] = __builtin_amdgcn_mfma_f32_16x16x32_bf16(a1n, wa, n2[nt], 0,0,0);
            n2[nt] = __builtin_amdgcn_mfma_f32_16x16x32_bf16(a2k, wb, n2[nt], 0,0,0);
        }
    }
    #pragma unroll
    for (int nt = 0; nt < 4; ++nt){
        int cc = nt*16 + lane16;
        #pragma unroll
        for (int i = 0; i < 4; ++i){
            int rr = w16 + quad*4 + i;
            int p = p0 + rr;
            float y = k2[nt][i] + n2[nt][i] + sb[192 + cc];
            float ay = fabsf(y) - 0.01f;           // softshrink lambda
            float r0 = ay > 0.f ? (y > 0.f ? ay : -ay) : 0.f;
            if (p < 64800) yout[(long long)p * 512 + kb*64 + cc] = f2bf(r0);
        }
    }
}

// ---------------- launch ----------------
extern "C" void kernel_launch(void* const* d_in, const int* in_sizes, int n_in,
                              void* d_out, int out_size, void* d_ws, size_t ws_size,
                              hipStream_t stream) {
    const float* x  = (const float*)d_in[0];
    const float* w1 = (const float*)d_in[1];
    const float* b1 = (const float*)d_in[2];
    const float* w2 = (const float*)d_in[3];
    const float* b2 = (const float*)d_in[4];
    float* out = (float*)d_out;

    u16* ws   = (u16*)d_ws;
    u16* casC = ws;                        // 262144
    u16* casW = casC + 262144;             // 360*384 = 138240
    u16* wts  = casW + 138240;             // 131072
    u16* bufT = wts  + 131072;             // 33177600 + 64 pad (T1 / y)
    u16* bufP = bufT + 33177664;           // 33177600 + 64 pad (xbf / xh / Z)
    // total ws ~133.8 MB

    prep<<<1024, 256, 0, stream>>>(w1, w2, casC, casW, wts);
    cvt_k<<<16200, 256, 0, stream>>>(x, bufP);   // xbf -> bufP (dead until B overwrites)

    dim3 gBig(2028, 1, 1);    // 507 row-blocks x 4 col-blocks, XCD-swizzled in-kernel
    dim3 gW(3, 4, 180);
    dim3 gM(1013, 8, 1);

    // A) T1[h][d][w] = (xbf . casC) transposed       (channel contraction)
    gemm_k<1,1><<<gBig, 256, 0, stream>>>(bufP, 512, 0, 64799,
                                          casC, 512, 0,
                                          bufT, 0, 64800, nullptr, 0.f, 16, 4);
    // B) xh[(h,v)][d] = sum_w casW[v][w] * T1[h][d][w]  (width contraction)
    gemm_k<0,0><<<gW, 256, 0, stream>>>(casW, 384, 0, 359,
                                        bufT, 360, (long long)PL,
                                        bufP, (long long)PL, 360, nullptr, 0.f, 12, 1);
    // C) block-MLP + softshrink: xh -> y
    mlp_k<<<gM, 256, 0, stream>>>(bufP, wts, b1, b2, bufT);
    // D) Z[h][d][w] = (y . casC) transposed
    gemm_k<1,1><<<gBig, 256, 0, stream>>>(bufT, 512, 0, 64799,
                                          casC, 512, 0,
                                          bufP, 0, 64800, nullptr, 0.f, 16, 4);
    // E) out[(h,v)][d] = (sum_w casW[v][w] * Z[h][d][w]) / 184320 + x
    gemm_k<2,0><<<gW, 256, 0, stream>>>(casW, 384, 0, 359,
                                        bufP, 360, (long long)PL,
                                        out, (long long)PL, 360,
                                        x, 1.0f/184320.0f, 12, 1);
}

// Round 7
// 759.630 us; speedup vs baseline: 1.0166x; 1.0166x over previous
//
#include <hip/hip_runtime.h>
#include <math.h>

// Problem constants
#define HH 180
#define WDIM 360
#define CDIM 512
#define NP 64800           // 180*360 positions
#define PL 184320          // 360*512 per-h plane (also idht norm)

typedef unsigned short u16;
typedef __attribute__((ext_vector_type(8))) short short8;  // 8 bf16 = 4 VGPR
typedef __attribute__((ext_vector_type(4))) float f4;      // 4 fp32 acc

__device__ __forceinline__ u16 f2bf(float f){
    unsigned u = __float_as_uint(f);
    return (u16)((u + 0x7fffu + ((u >> 16) & 1u)) >> 16);   // RNE
}
__device__ __forceinline__ void gl_lds16(const void* g, void* l){
    __builtin_amdgcn_global_load_lds((const __attribute__((address_space(1))) void*)g,
                                     (__attribute__((address_space(3))) void*)l, 16, 0, 0);
}

// ---------------- prep: cas matrices (bf16) + folded transposed weights ----------------
__global__ void prep(const float* __restrict__ w1, const float* __restrict__ w2,
                     u16* __restrict__ casC, u16* __restrict__ casW, u16* __restrict__ wts,
                     u16* __restrict__ padT, u16* __restrict__ padP)
{
    int idx = blockIdx.x * 256 + threadIdx.x;
    if (idx < 64){ padT[idx] = 0; padP[idx] = 0; }          // zero buffer pads (K-overread safety)
    if (idx < 512*512){
        int i = idx >> 9, j = idx & 511;
        int m = (i * j) & 511;                       // exact angle reduction
        float a = (float)m * (6.283185307179586f / 512.0f);
        float s, c; __sincosf(a, &s, &c);
        casC[idx] = f2bf(c + s);
    }
    if (idx < 360*384){
        int i = idx / 384, j = idx - (idx / 384) * 384;
        u16 v = 0;
        if (j < 360){
            int m = (i * j) % 360;
            float a = (float)m * (6.283185307179586f / 360.0f);
            float s, c; __sincosf(a, &s, &c);
            v = f2bf(c + s);
        }
        casW[idx] = v;
    }
    if (idx < 131072){
        int s = idx >> 15, r = idx & 32767;
        int kb = r >> 12, o = (r >> 6) & 63, ii = r & 63;
        const float* w = (s < 2) ? w1 : w2;
        float v0 = w[kb*4096 + ii*64 + o];
        float v1 = w[32768 + kb*4096 + ii*64 + o];
        float v = 0.5f * ((s & 1) ? (v0 - v1) : (v0 + v1));
        wts[idx] = f2bf(v);
    }
}

// ---------------- x (fp32) -> bf16, RNE ----------------
__global__ __launch_bounds__(256)
void cvt_k(const float* __restrict__ x, u16* __restrict__ xb)
{
    long long i = ((long long)blockIdx.x * 256 + threadIdx.x) * 8;
    float4 a = *(const float4*)(x + i);
    float4 b = *(const float4*)(x + i + 4);
    uint4 w;
    w.x = (unsigned)f2bf(a.x) | ((unsigned)f2bf(a.y) << 16);
    w.y = (unsigned)f2bf(a.z) | ((unsigned)f2bf(a.w) << 16);
    w.z = (unsigned)f2bf(b.x) | ((unsigned)f2bf(b.y) << 16);
    w.w = (unsigned)f2bf(b.z) | ((unsigned)f2bf(b.w) << 16);
    *(uint4*)(xb + i) = w;
}

// ---------------- big GEMM (A/D): C = A(Mx512) * casC^T, transposed store ----------------
// 128x128 tile, 4 waves, 3-deep counted-vmcnt pipeline (verified in R3 bench).
template<int STORE, int SWAP>
__global__ __launch_bounds__(256)
void gemm_k(const u16* __restrict__ A, int ldA, long long sA, int clampA,
            const u16* __restrict__ B, int ldB, long long sB,
            void* __restrict__ C, long long sC, int Mreal,
            const float* __restrict__ X, float scale, int nK, int nbx)
{
    __shared__ u16 As[3][4096];   // [buf][4 chunks][128 rows][8]
    __shared__ u16 Bs[3][4096];

    const int tid = threadIdx.x, wv = tid >> 6, l = tid & 63;
    const int l16 = l & 15, quad = l >> 4;
    const int z = blockIdx.z;

    int bx, by;
    if constexpr (SWAP){
        int n = gridDim.x;
        int q = n >> 3, r = n & 7;
        int xcd = blockIdx.x & 7, idx = blockIdx.x >> 3;
        int swz = (xcd < r ? xcd*(q+1) : r*(q+1) + (xcd-r)*q) + idx;
        bx = swz / nbx;            // row-block
        by = swz - bx * nbx;       // col-block (fastest within XCD chunk)
    } else {
        bx = blockIdx.x;
        by = blockIdx.y;
    }
    const int row0 = bx * 128, col0 = by * 128;

    const int rh = wv & 1, c0 = wv >> 1;

    const u16* gB = B + sB * z + (long long)(col0 + rh*64 + l) * ldB;
    int ar = row0 + rh*64 + l; ar = ar <= clampA ? ar : clampA;
    const u16* gA = A + sA * z + (long long)ar * ldA;

    f4 acc[4][4];
    #pragma unroll
    for (int mt = 0; mt < 4; ++mt)
        #pragma unroll
        for (int nt = 0; nt < 4; ++nt)
            acc[mt][nt] = (f4)0.0f;

    const int mrow = (wv >> 1) * 64, ncol = (wv & 1) * 64;

    #define STAGE(buf, kt) do{ const int k0_ = (kt)*32;                          \
        gl_lds16(gB + k0_ + c0*8,     &Bs[buf][c0*1024     + rh*512]);           \
        gl_lds16(gB + k0_ + (c0+2)*8, &Bs[buf][(c0+2)*1024 + rh*512]);           \
        gl_lds16(gA + k0_ + c0*8,     &As[buf][c0*1024     + rh*512]);           \
        gl_lds16(gA + k0_ + (c0+2)*8, &As[buf][(c0+2)*1024 + rh*512]); }while(0)

    STAGE(0, 0);
    STAGE(1, 1);
    STAGE(2, 2);

    int cur = 0;
    for (int kt = 0; kt < nK; ++kt){
        asm volatile("s_waitcnt vmcnt(8)" ::: "memory");
        __builtin_amdgcn_s_barrier();
        __builtin_amdgcn_sched_barrier(0);

        short8 af[4];
        #pragma unroll
        for (int mt = 0; mt < 4; ++mt)
            af[mt] = *(const short8*)&As[cur][quad*1024 + (mrow + mt*16 + l16)*8];
        #pragma unroll
        for (int nt = 0; nt < 4; ++nt){
            short8 bfv = *(const short8*)&Bs[cur][quad*1024 + (ncol + nt*16 + l16)*8];
            #pragma unroll
            for (int mt = 0; mt < 4; ++mt)
                acc[mt][nt] = __builtin_amdgcn_mfma_f32_16x16x32_bf16(af[mt], bfv, acc[mt][nt], 0, 0, 0);
        }

        __builtin_amdgcn_sched_barrier(0);
        __builtin_amdgcn_s_barrier();
        __builtin_amdgcn_sched_barrier(0);

        int nxt = kt + 3; if (nxt > nK - 1) nxt = nK - 1;
        STAGE(cur, nxt);
        cur = (cur == 2) ? 0 : cur + 1;
    }
    #undef STAGE

    // epilogue: C/D layout col=lane&15, row=quad*4+reg
    #pragma unroll
    for (int mt = 0; mt < 4; ++mt){
        #pragma unroll
        for (int i = 0; i < 4; ++i){
            int gr = row0 + mrow + mt*16 + quad*4 + i;
            if (gr >= Mreal) continue;
            int th = 0, tw = 0;
            if constexpr (STORE == 1){ th = gr / 360; tw = gr - th * 360; }
            #pragma unroll
            for (int nt = 0; nt < 4; ++nt){
                int gc = col0 + ncol + nt*16 + l16;
                if constexpr (STORE == 0){
                    ((u16*)C)[sC*z + (long long)gr*512 + gc] = f2bf(acc[mt][nt][i]);
                } else if constexpr (STORE == 1){
                    ((u16*)C)[((long long)th*512 + gc)*360 + tw] = f2bf(acc[mt][nt][i]);
                } else {
                    long long off = sC*z + (long long)gr*512 + gc;
                    ((float*)C)[off] = fmaf(acc[mt][nt][i], scale, X[off]);
                }
            }
        }
    }
}

// ---------------- w-contraction GEMM (B/E): persistent casW panel, multi-plane ----------------
// out[z][v][d] = sum_w casW[v][w] * S[z][d][w]   for 5 consecutive planes per block.
// 512 threads (8 waves, 2m x 4n), tile 128v x 256d.
// casW panel [12 kt][4 c][128 r][8] = 96KB staged ONCE; B-tiles [2 buf][4 c][256 r][8] = 32KB.
// Total LDS = 128KB (HW-verified footprint, m201). 2-deep counted-vmcnt pipeline
// running 60 K-steps continuously across plane boundaries.
// STORE=0: bf16 xh[p][d].  STORE=2: fp32 out = acc*scale + X (residual).
template<int STORE>
__global__ __launch_bounds__(512)
void wgemm_k(const u16* __restrict__ A, const u16* __restrict__ Bsrc,
             void* __restrict__ C, const float* __restrict__ X, float scale)
{
    __shared__ u16 As[49152];     // [12 kt][4 c][128 r][8] = 96KB
    __shared__ u16 Bs[2][8192];   // [4 c][256 r][8]        = 32KB

    const int tid = threadIdx.x, wv = tid >> 6, l = tid & 63;
    const int l16 = l & 15, quad = l >> 4;

    // m204 swizzle (216 % 8 == 0 -> q=27), bx fastest within an XCD chunk
    const int q = gridDim.x >> 3;
    const int swz = (blockIdx.x & 7) * q + (blockIdx.x >> 3);
    const int bx = swz % 3;
    const int g  = swz / 3;        // [0,72)
    const int zs = g % 36, by = g / 36;
    const int row0 = bx * 128, col0 = by * 256, z0 = zs * 5;

    const int wm = wv >> 2, wn = wv & 3;
    const int mrow = wm * 64, ncol = wn * 64;

    // ---- stage casW panel once: 96 x 1KB segments, wave wv takes s = wv + 8j ----
    #pragma unroll
    for (int j = 0; j < 12; ++j){
        int s = wv + 8*j;
        int kt = s >> 3, c = (s >> 1) & 3, half = s & 1;
        int gr = row0 + half*64 + l; gr = gr <= 359 ? gr : 359;
        gl_lds16(A + (long long)gr*384 + kt*32 + c*8,
                 &As[kt*4096 + c*1024 + half*512]);
    }

    // ---- B-tile staging: 16 x 1KB segments per tile, wave wv takes 2 (hand-unrolled) ----
    #define WSTAGE(buf, t) do{                                                     \
        int z_ = z0 + (t)/12, kt_ = (t) - ((t)/12)*12;                             \
        const u16* zb_ = Bsrc + (long long)z_ * PL + kt_*32;                       \
        int s0_ = wv*2,   c0_ = s0_ >> 2, q0_ = s0_ & 3;                           \
        gl_lds16(zb_ + (long long)(col0 + q0_*64 + l)*360 + c0_*8,                 \
                 &Bs[buf][c0_*2048 + q0_*512]);                                    \
        int s1_ = wv*2+1, c1_ = s1_ >> 2, q1_ = s1_ & 3;                           \
        gl_lds16(zb_ + (long long)(col0 + q1_*64 + l)*360 + c1_*8,                 \
                 &Bs[buf][c1_*2048 + q1_*512]); }while(0)

    WSTAGE(0, 0);
    WSTAGE(1, 1);

    f4 acc[4][4];
    #pragma unroll
    for (int mt = 0; mt < 4; ++mt)
        #pragma unroll
        for (int nt = 0; nt < 4; ++nt)
            acc[mt][nt] = (f4)0.0f;

    const int T = 60;             // 5 planes x 12 k-steps
    int kt = 0, buf = 0, zi = 0;
    for (int t = 0; t < T; ++t){
        // own tile-t loads landed (2 = one tile x 2 segs still outstanding);
        // first iter this also drains the 12 casW-panel ops.
        asm volatile("s_waitcnt vmcnt(2)" ::: "memory");
        __builtin_amdgcn_s_barrier();
        __builtin_amdgcn_sched_barrier(0);

        short8 af[4];
        #pragma unroll
        for (int mt = 0; mt < 4; ++mt)
            af[mt] = *(const short8*)&As[kt*4096 + quad*1024 + (mrow + mt*16 + l16)*8];
        #pragma unroll
        for (int nt = 0; nt < 4; ++nt){
            short8 bfv = *(const short8*)&Bs[buf][quad*2048 + (ncol + nt*16 + l16)*8];
            #pragma unroll
            for (int mt = 0; mt < 4; ++mt)
                acc[mt][nt] = __builtin_amdgcn_mfma_f32_16x16x32_bf16(af[mt], bfv, acc[mt][nt], 0, 0, 0);
        }

        __builtin_amdgcn_sched_barrier(0);
        __builtin_amdgcn_s_barrier();
        __builtin_amdgcn_sched_barrier(0);

        int nxt = t + 2; if (nxt > T - 1) nxt = T - 1;   // clamp: no OOB global reads
        WSTAGE(buf, nxt);

        if (kt == 11){
            // ---- per-plane epilogue (acc-only; no LDS, no barrier needed) ----
            const int z = z0 + zi;
            #pragma unroll
            for (int mt = 0; mt < 4; ++mt){
                #pragma unroll
                for (int i = 0; i < 4; ++i){
                    int gr = row0 + mrow + mt*16 + quad*4 + i;
                    if (gr < 360){
                        long long base = ((long long)z*360 + gr)*512;
                        #pragma unroll
                        for (int nt = 0; nt < 4; ++nt){
                            int gc = col0 + ncol + nt*16 + l16;
                            if constexpr (STORE == 0){
                                ((u16*)C)[base + gc] = f2bf(acc[mt][nt][i]);
                            } else {
                                ((float*)C)[base + gc] = fmaf(acc[mt][nt][i], scale, X[base + gc]);
                            }
                        }
                    }
                }
            }
            #pragma unroll
            for (int mt = 0; mt < 4; ++mt)
                #pragma unroll
                for (int nt = 0; nt < 4; ++nt)
                    acc[mt][nt] = (f4)0.0f;
            ++zi;
            kt = 0;
        } else {
            ++kt;
        }
        buf ^= 1;
    }
    #undef WSTAGE
}

// ---------------- MFMA block-MLP + softshrink ----------------
__global__ __launch_bounds__(256)
void mlp_k(const u16* __restrict__ xh, const u16* __restrict__ wts,
           const float* __restrict__ b1, const float* __restrict__ b2,
           u16* __restrict__ yout)
{
    __shared__ u16 sW0[64*72], sW1[64*72];
    __shared__ u16 sXh[64*72], sXn[64*72], s1k[64*72], s1n[64*72];
    __shared__ float sb[256];

    const int tid = threadIdx.x;
    const int wv = tid >> 6, l = tid & 63, lane16 = l & 15, quad = l >> 4;
    const int kb = blockIdx.y;
    const int p0 = blockIdx.x * 64;
    const int w16 = wv * 16;

    if (tid < 64){
        sb[tid]       = b1[kb*64 + tid];
        sb[64 + tid]  = b1[512 + kb*64 + tid];
        sb[128 + tid] = b2[kb*64 + tid];
        sb[192 + tid] = b2[512 + kb*64 + tid];
    }
    {
        const int r = tid >> 2, sg = (tid & 3) * 16;
        const u16* s0 = wts + kb*4096 + r*64 + sg;            // w1a_t
        const u16* s1 = wts + 32768 + kb*4096 + r*64 + sg;    // w1b_t
        *(uint4*)&sW0[r*72 + sg]     = *(const uint4*)s0;
        *(uint4*)&sW0[r*72 + sg + 8] = *(const uint4*)(s0 + 8);
        *(uint4*)&sW1[r*72 + sg]     = *(const uint4*)s1;
        *(uint4*)&sW1[r*72 + sg + 8] = *(const uint4*)(s1 + 8);

        int p = p0 + r; int pc = p <= 64799 ? p : 64799;
        int h = pc / 360; int v = pc - h * 360;
        int hn = (h == 0) ? 0 : (180 - h);
        int vn = (v == 0) ? 0 : (360 - v);
        long long bh = (long long)pc * 512 + kb*64 + sg;
        long long bn = (long long)(hn*360 + vn) * 512 + kb*64 + sg;
        *(uint4*)&sXh[r*72 + sg]     = *(const uint4*)&xh[bh];
        *(uint4*)&sXh[r*72 + sg + 8] = *(const uint4*)&xh[bh + 8];
        *(uint4*)&sXn[r*72 + sg]     = *(const uint4*)&xh[bn];
        *(uint4*)&sXn[r*72 + sg + 8] = *(const uint4*)&xh[bn + 8];
    }
    __syncthreads();

    // -------- layer 1 --------
    f4 aK[4], aN[4];
    #pragma unroll
    for (int nt = 0; nt < 4; ++nt){ aK[nt] = (f4)0.0f; aN[nt] = (f4)0.0f; }
    #pragma unroll
    for (int kq = 0; kq < 2; ++kq){
        short8 fxh = *(const short8*)&sXh[(w16 + lane16)*72 + kq*32 + quad*8];
        short8 fxn = *(const short8*)&sXn[(w16 + lane16)*72 + kq*32 + quad*8];
        #pragma unroll
        for (int nt = 0; nt < 4; ++nt){
            short8 wa = *(const short8*)&sW0[(nt*16 + lane16)*72 + kq*32 + quad*8];
            short8 wb = *(const short8*)&sW1[(nt*16 + lane16)*72 + kq*32 + quad*8];
            aK[nt] = __builtin_amdgcn_mfma_f32_16x16x32_bf16(fxh, wa, aK[nt], 0,0,0);
            aK[nt] = __builtin_amdgcn_mfma_f32_16x16x32_bf16(fxn, wb, aK[nt], 0,0,0);
            aN[nt] = __builtin_amdgcn_mfma_f32_16x16x32_bf16(fxn, wa, aN[nt], 0,0,0);
            aN[nt] = __builtin_amdgcn_mfma_f32_16x16x32_bf16(fxh, wb, aN[nt], 0,0,0);
        }
    }
    #pragma unroll
    for (int nt = 0; nt < 4; ++nt){
        int cc = nt*16 + lane16;
        #pragma unroll
        for (int i = 0; i < 4; ++i){
            int rr = w16 + quad*4 + i;
            float vk = fmaxf(aK[nt][i] + sb[cc], 0.f);
            float vn = fmaxf(aN[nt][i] + sb[64 + cc], 0.f);
            s1k[rr*72 + cc] = f2bf(vk);
            s1n[rr*72 + cc] = f2bf(vn);
        }
    }
    __syncthreads();

    // -------- swap weights to layer 2 --------
    {
        const int r = tid >> 2, sg = (tid & 3) * 16;
        const u16* s0 = wts + 65536 + kb*4096 + r*64 + sg;    // w2a_t
        const u16* s1 = wts + 98304 + kb*4096 + r*64 + sg;    // w2b_t
        *(uint4*)&sW0[r*72 + sg]     = *(const uint4*)s0;
        *(uint4*)&sW0[r*72 + sg + 8] = *(const uint4*)(s0 + 8);
        *(uint4*)&sW1[r*72 + sg]     = *(const uint4*)s1;
        *(uint4*)&sW1[r*72 + sg + 8] = *(const uint4*)(s1 + 8);
    }
    __syncthreads();

    // -------- layer 2a: o2k --------
    f4 k2[4];
    #pragma unroll
    for (int nt = 0; nt < 4; ++nt) k2[nt] = (f4)0.0f;
    #pragma unroll
    for (int kq = 0; kq < 2; ++kq){
        short8 a1k = *(const short8*)&s1k[(w16 + lane16)*72 + kq*32 + quad*8];
        short8 a1n = *(const short8*)&s1n[(w16 + lane16)*72 + kq*32 + quad*8];
        #pragma unroll
        for (int nt = 0; nt < 4; ++nt){
            short8 wa = *(const short8*)&sW0[(nt*16 + lane16)*72 + kq*32 + quad*8];
            short8 wb = *(const short8*)&sW1[(nt*16 + lane16)*72 + kq*32 + quad*8];
            k2[nt] = __builtin_amdgcn_mfma_f32_16x16x32_bf16(a1k, wa, k2[nt], 0,0,0);
            k2[nt] = __builtin_amdgcn_mfma_f32_16x16x32_bf16(a1n, wb, k2[nt], 0,0,0);
        }
    }
    #pragma unroll
    for (int nt = 0; nt < 4; ++nt){
        int cc = nt*16 + lane16;
        #pragma unroll
        for (int i = 0; i < 4; ++i){
            int rr = w16 + quad*4 + i;
            float v2 = k2[nt][i] + sb[128 + cc];
            k2[nt][i] = v2;                        // keep o2k (with bias) in regs
            sXh[rr*72 + cc] = f2bf(v2);            // reuse sXh as o2k A-operand
        }
    }
    __syncthreads();

    // -------- layer 2b: o2n (consumes o2k per source bug) + softshrink --------
    f4 n2[4];
    #pragma unroll
    for (int nt = 0; nt < 4; ++nt) n2[nt] = (f4)0.0f;
    #pragma unroll
    for (int kq = 0; kq < 2; ++kq){
        short8 a1n = *(const short8*)&s1n[(w16 + lane16)*72 + kq*32 + quad*8];
        short8 a2k = *(const short8*)&sXh[(w16 + lane16)*72 + kq*32 + quad*8];
        #pragma unroll
        for (int nt = 0; nt < 4; ++nt){
            short8 wa = *(const short8*)&sW0[(nt*16 + lane16)*72 + kq*32 + quad*8];
            short8 wb = *(const short8*)&sW1[(nt*16 + lane16)*72 + kq*32 + quad*8];
            n2[nt] = __builtin_amdgcn_mfma_f32_16x16x32_bf16(a1n, wa, n2[nt], 0,0,0);
            n2[nt] = __builtin_amdgcn_mfma_f32_16x16x32_bf16(a2k, wb, n2[nt], 0,0,0);
        }
    }
    #pragma unroll
    for (int nt = 0; nt < 4; ++nt){
        int cc = nt*16 + lane16;
        #pragma unroll
        for (int i = 0; i < 4; ++i){
            int rr = w16 + quad*4 + i;
            int p = p0 + rr;
            float y = k2[nt][i] + n2[nt][i] + sb[192 + cc];
            float ay = fabsf(y) - 0.01f;           // softshrink lambda
            float r0 = ay > 0.f ? (y > 0.f ? ay : -ay) : 0.f;
            if (p < 64800) yout[(long long)p * 512 + kb*64 + cc] = f2bf(r0);
        }
    }
}

// ---------------- launch ----------------
extern "C" void kernel_launch(void* const* d_in, const int* in_sizes, int n_in,
                              void* d_out, int out_size, void* d_ws, size_t ws_size,
                              hipStream_t stream) {
    const float* x  = (const float*)d_in[0];
    const float* w1 = (const float*)d_in[1];
    const float* b1 = (const float*)d_in[2];
    const float* w2 = (const float*)d_in[3];
    const float* b2 = (const float*)d_in[4];
    float* out = (float*)d_out;

    u16* ws   = (u16*)d_ws;
    u16* casC = ws;                        // 262144
    u16* casW = casC + 262144;             // 360*384 = 138240
    u16* wts  = casW + 138240;             // 131072
    u16* bufT = wts  + 131072;             // 33177600 + 64 pad (T1 / y)
    u16* bufP = bufT + 33177664;           // 33177600 + 64 pad (xbf / xh / Z)
    // total ws ~133.8 MB

    prep<<<1024, 256, 0, stream>>>(w1, w2, casC, casW, wts,
                                   bufT + 33177600, bufP + 33177600);
    cvt_k<<<16200, 256, 0, stream>>>(x, bufP);   // xbf -> bufP (dead until B overwrites)

    dim3 gBig(2028, 1, 1);    // 507 row-blocks x 4 col-blocks, XCD-swizzled in-kernel
    dim3 gWg(216, 1, 1);      // 3 bx x 2 by x 36 z-chunks (5 planes each)
    dim3 gM(1013, 8, 1);

    // A) T1[h][d][w] = (xbf . casC) transposed       (channel contraction)
    gemm_k<1,1><<<gBig, 256, 0, stream>>>(bufP, 512, 0, 64799,
                                          casC, 512, 0,
                                          bufT, 0, 64800, nullptr, 0.f, 16, 4);
    // B) xh[(h,v)][d] = sum_w casW[v][w] * T1[h][d][w]  (width contraction)
    wgemm_k<0><<<gWg, 512, 0, stream>>>(casW, bufT, bufP, nullptr, 0.f);
    // C) block-MLP + softshrink: xh -> y
    mlp_k<<<gM, 256, 0, stream>>>(bufP, wts, b1, b2, bufT);
    // D) Z[h][d][w] = (y . casC) transposed
    gemm_k<1,1><<<gBig, 256, 0, stream>>>(bufT, 512, 0, 64799,
                                          casC, 512, 0,
                                          bufP, 0, 64800, nullptr, 0.f, 16, 4);
    // E) out[(h,v)][d] = (sum_w casW[v][w] * Z[h][d][w]) / 184320 + x
    wgemm_k<2><<<gWg, 512, 0, stream>>>(casW, bufP, out, x, 1.0f/184320.0f);
}

// Round 8
// 685.118 us; speedup vs baseline: 1.1272x; 1.1088x over previous
//
#include <hip/hip_runtime.h>
#include <math.h>

// Problem constants
#define HH 180
#define WDIM 360
#define CDIM 512
#define NP 64800           // 180*360 positions
#define PL 184320          // 360*512 per-h plane (also idht norm)

typedef unsigned short u16;
typedef __attribute__((ext_vector_type(8))) short short8;  // 8 bf16 = 4 VGPR
typedef __attribute__((ext_vector_type(4))) float f4;      // 4 fp32 acc

__device__ __forceinline__ u16 f2bf(float f){
    unsigned u = __float_as_uint(f);
    return (u16)((u + 0x7fffu + ((u >> 16) & 1u)) >> 16);   // RNE
}
__device__ __forceinline__ void gl_lds16(const void* g, void* l){
    __builtin_amdgcn_global_load_lds((const __attribute__((address_space(1))) void*)g,
                                     (__attribute__((address_space(3))) void*)l, 16, 0, 0);
}

// ---------------- prep: cas matrices (bf16) + folded transposed weights ----------------
__global__ void prep(const float* __restrict__ w1, const float* __restrict__ w2,
                     u16* __restrict__ casC, u16* __restrict__ casW, u16* __restrict__ wts,
                     u16* __restrict__ padT, u16* __restrict__ padP)
{
    int idx = blockIdx.x * 256 + threadIdx.x;
    if (idx < 64){ padT[idx] = 0; padP[idx] = 0; }          // zero buffer pads (K-overread safety)
    if (idx < 512*512){
        int i = idx >> 9, j = idx & 511;
        int m = (i * j) & 511;                       // exact angle reduction
        float a = (float)m * (6.283185307179586f / 512.0f);
        float s, c; __sincosf(a, &s, &c);
        casC[idx] = f2bf(c + s);
    }
    if (idx < 360*384){
        int i = idx / 384, j = idx - (idx / 384) * 384;
        u16 v = 0;
        if (j < 360){
            int m = (i * j) % 360;
            float a = (float)m * (6.283185307179586f / 360.0f);
            float s, c; __sincosf(a, &s, &c);
            v = f2bf(c + s);
        }
        casW[idx] = v;
    }
    if (idx < 131072){
        int s = idx >> 15, r = idx & 32767;
        int kb = r >> 12, o = (r >> 6) & 63, ii = r & 63;
        const float* w = (s < 2) ? w1 : w2;
        float v0 = w[kb*4096 + ii*64 + o];
        float v1 = w[32768 + kb*4096 + ii*64 + o];
        float v = 0.5f * ((s & 1) ? (v0 - v1) : (v0 + v1));
        wts[idx] = f2bf(v);
    }
}

// ---------------- x (fp32) -> bf16, RNE ----------------
__global__ __launch_bounds__(256)
void cvt_k(const float* __restrict__ x, u16* __restrict__ xb)
{
    long long i = ((long long)blockIdx.x * 256 + threadIdx.x) * 8;
    float4 a = *(const float4*)(x + i);
    float4 b = *(const float4*)(x + i + 4);
    uint4 w;
    w.x = (unsigned)f2bf(a.x) | ((unsigned)f2bf(a.y) << 16);
    w.y = (unsigned)f2bf(a.z) | ((unsigned)f2bf(a.w) << 16);
    w.z = (unsigned)f2bf(b.x) | ((unsigned)f2bf(b.y) << 16);
    w.w = (unsigned)f2bf(b.z) | ((unsigned)f2bf(b.w) << 16);
    *(uint4*)(xb + i) = w;
}

// ---------------- big GEMM (A/D): C = A(Mx512) * casC^T, transposed store ----------------
// 128x128 tile, 4 waves, 3-deep counted-vmcnt pipeline (verified R3/R7).
// STORE=1 epilogue: acc[..][i] i=0..3 are 4 CONSECUTIVE w (m-dim) values; since the
// pack start and 360 are both =0 mod 4, a 4-pack never crosses an h boundary and the
// byte address is 8B-aligned -> single uint2 store (4x fewer L2 transactions than the
// old per-u16 scatter, which is the transaction-rate bottleneck theory for A/D).
template<int STORE, int SWAP>
__global__ __launch_bounds__(256)
void gemm_k(const u16* __restrict__ A, int ldA, long long sA, int clampA,
            const u16* __restrict__ B, int ldB, long long sB,
            void* __restrict__ C, long long sC, int Mreal,
            const float* __restrict__ X, float scale, int nK, int nbx)
{
    __shared__ u16 As[3][4096];   // [buf][4 chunks][128 rows][8]
    __shared__ u16 Bs[3][4096];

    const int tid = threadIdx.x, wv = tid >> 6, l = tid & 63;
    const int l16 = l & 15, quad = l >> 4;
    const int z = blockIdx.z;

    int bx, by;
    if constexpr (SWAP){
        int n = gridDim.x;
        int q = n >> 3, r = n & 7;
        int xcd = blockIdx.x & 7, idx = blockIdx.x >> 3;
        int swz = (xcd < r ? xcd*(q+1) : r*(q+1) + (xcd-r)*q) + idx;
        bx = swz / nbx;            // row-block
        by = swz - bx * nbx;       // col-block (fastest within XCD chunk)
    } else {
        bx = blockIdx.x;
        by = blockIdx.y;
    }
    const int row0 = bx * 128, col0 = by * 128;

    const int rh = wv & 1, c0 = wv >> 1;

    const u16* gB = B + sB * z + (long long)(col0 + rh*64 + l) * ldB;
    int ar = row0 + rh*64 + l; ar = ar <= clampA ? ar : clampA;
    const u16* gA = A + sA * z + (long long)ar * ldA;

    f4 acc[4][4];
    #pragma unroll
    for (int mt = 0; mt < 4; ++mt)
        #pragma unroll
        for (int nt = 0; nt < 4; ++nt)
            acc[mt][nt] = (f4)0.0f;

    const int mrow = (wv >> 1) * 64, ncol = (wv & 1) * 64;

    #define STAGE(buf, kt) do{ const int k0_ = (kt)*32;                          \
        gl_lds16(gB + k0_ + c0*8,     &Bs[buf][c0*1024     + rh*512]);           \
        gl_lds16(gB + k0_ + (c0+2)*8, &Bs[buf][(c0+2)*1024 + rh*512]);           \
        gl_lds16(gA + k0_ + c0*8,     &As[buf][c0*1024     + rh*512]);           \
        gl_lds16(gA + k0_ + (c0+2)*8, &As[buf][(c0+2)*1024 + rh*512]); }while(0)

    STAGE(0, 0);
    STAGE(1, 1);
    STAGE(2, 2);

    int cur = 0;
    for (int kt = 0; kt < nK; ++kt){
        asm volatile("s_waitcnt vmcnt(8)" ::: "memory");
        __builtin_amdgcn_s_barrier();
        __builtin_amdgcn_sched_barrier(0);

        short8 af[4];
        #pragma unroll
        for (int mt = 0; mt < 4; ++mt)
            af[mt] = *(const short8*)&As[cur][quad*1024 + (mrow + mt*16 + l16)*8];
        #pragma unroll
        for (int nt = 0; nt < 4; ++nt){
            short8 bfv = *(const short8*)&Bs[cur][quad*1024 + (ncol + nt*16 + l16)*8];
            #pragma unroll
            for (int mt = 0; mt < 4; ++mt)
                acc[mt][nt] = __builtin_amdgcn_mfma_f32_16x16x32_bf16(af[mt], bfv, acc[mt][nt], 0, 0, 0);
        }

        __builtin_amdgcn_sched_barrier(0);
        __builtin_amdgcn_s_barrier();
        __builtin_amdgcn_sched_barrier(0);

        int nxt = kt + 3; if (nxt > nK - 1) nxt = nK - 1;
        STAGE(cur, nxt);
        cur = (cur == 2) ? 0 : cur + 1;
    }
    #undef STAGE

    // epilogue: C/D layout col=lane&15, row=quad*4+reg
    if constexpr (STORE == 1){
        // packed transposed store: 4 consecutive w per uint2
        #pragma unroll
        for (int mt = 0; mt < 4; ++mt){
            int gr0 = row0 + mrow + mt*16 + quad*4;       // = 0 mod 4
            if (gr0 < Mreal){
                int th = gr0 / 360, tw0 = gr0 - th * 360; // tw0 <= 356 always (360%4==0)
                #pragma unroll
                for (int nt = 0; nt < 4; ++nt){
                    int gc = col0 + ncol + nt*16 + l16;
                    uint2 pk;
                    pk.x = (unsigned)f2bf(acc[mt][nt][0]) | ((unsigned)f2bf(acc[mt][nt][1]) << 16);
                    pk.y = (unsigned)f2bf(acc[mt][nt][2]) | ((unsigned)f2bf(acc[mt][nt][3]) << 16);
                    *(uint2*)&((u16*)C)[((long long)th*512 + gc)*360 + tw0] = pk;
                }
            }
        }
    } else {
        #pragma unroll
        for (int mt = 0; mt < 4; ++mt){
            #pragma unroll
            for (int i = 0; i < 4; ++i){
                int gr = row0 + mrow + mt*16 + quad*4 + i;
                if (gr >= Mreal) continue;
                #pragma unroll
                for (int nt = 0; nt < 4; ++nt){
                    int gc = col0 + ncol + nt*16 + l16;
                    if constexpr (STORE == 0){
                        ((u16*)C)[sC*z + (long long)gr*512 + gc] = f2bf(acc[mt][nt][i]);
                    } else {
                        long long off = sC*z + (long long)gr*512 + gc;
                        ((float*)C)[off] = fmaf(acc[mt][nt][i], scale, X[off]);
                    }
                }
            }
        }
    }
}

// ---------------- w-contraction GEMM (B/E): persistent casW panel, multi-plane ----------------
// (unchanged from R7-verified source)
template<int STORE>
__global__ __launch_bounds__(512)
void wgemm_k(const u16* __restrict__ A, const u16* __restrict__ Bsrc,
             void* __restrict__ C, const float* __restrict__ X, float scale)
{
    __shared__ u16 As[49152];     // [12 kt][4 c][128 r][8] = 96KB
    __shared__ u16 Bs[2][8192];   // [4 c][256 r][8]        = 32KB

    const int tid = threadIdx.x, wv = tid >> 6, l = tid & 63;
    const int l16 = l & 15, quad = l >> 4;

    const int q = gridDim.x >> 3;
    const int swz = (blockIdx.x & 7) * q + (blockIdx.x >> 3);
    const int bx = swz % 3;
    const int g  = swz / 3;        // [0,72)
    const int zs = g % 36, by = g / 36;
    const int row0 = bx * 128, col0 = by * 256, z0 = zs * 5;

    const int wm = wv >> 2, wn = wv & 3;
    const int mrow = wm * 64, ncol = wn * 64;

    #pragma unroll
    for (int j = 0; j < 12; ++j){
        int s = wv + 8*j;
        int kt = s >> 3, c = (s >> 1) & 3, half = s & 1;
        int gr = row0 + half*64 + l; gr = gr <= 359 ? gr : 359;
        gl_lds16(A + (long long)gr*384 + kt*32 + c*8,
                 &As[kt*4096 + c*1024 + half*512]);
    }

    #define WSTAGE(buf, t) do{                                                     \
        int z_ = z0 + (t)/12, kt_ = (t) - ((t)/12)*12;                             \
        const u16* zb_ = Bsrc + (long long)z_ * PL + kt_*32;                       \
        int s0_ = wv*2,   c0_ = s0_ >> 2, q0_ = s0_ & 3;                           \
        gl_lds16(zb_ + (long long)(col0 + q0_*64 + l)*360 + c0_*8,                 \
                 &Bs[buf][c0_*2048 + q0_*512]);                                    \
        int s1_ = wv*2+1, c1_ = s1_ >> 2, q1_ = s1_ & 3;                           \
        gl_lds16(zb_ + (long long)(col0 + q1_*64 + l)*360 + c1_*8,                 \
                 &Bs[buf][c1_*2048 + q1_*512]); }while(0)

    WSTAGE(0, 0);
    WSTAGE(1, 1);

    f4 acc[4][4];
    #pragma unroll
    for (int mt = 0; mt < 4; ++mt)
        #pragma unroll
        for (int nt = 0; nt < 4; ++nt)
            acc[mt][nt] = (f4)0.0f;

    const int T = 60;             // 5 planes x 12 k-steps
    int kt = 0, buf = 0, zi = 0;
    for (int t = 0; t < T; ++t){
        asm volatile("s_waitcnt vmcnt(2)" ::: "memory");
        __builtin_amdgcn_s_barrier();
        __builtin_amdgcn_sched_barrier(0);

        short8 af[4];
        #pragma unroll
        for (int mt = 0; mt < 4; ++mt)
            af[mt] = *(const short8*)&As[kt*4096 + quad*1024 + (mrow + mt*16 + l16)*8];
        #pragma unroll
        for (int nt = 0; nt < 4; ++nt){
            short8 bfv = *(const short8*)&Bs[buf][quad*2048 + (ncol + nt*16 + l16)*8];
            #pragma unroll
            for (int mt = 0; mt < 4; ++mt)
                acc[mt][nt] = __builtin_amdgcn_mfma_f32_16x16x32_bf16(af[mt], bfv, acc[mt][nt], 0, 0, 0);
        }

        __builtin_amdgcn_sched_barrier(0);
        __builtin_amdgcn_s_barrier();
        __builtin_amdgcn_sched_barrier(0);

        int nxt = t + 2; if (nxt > T - 1) nxt = T - 1;   // clamp: no OOB global reads
        WSTAGE(buf, nxt);

        if (kt == 11){
            const int z = z0 + zi;
            #pragma unroll
            for (int mt = 0; mt < 4; ++mt){
                #pragma unroll
                for (int i = 0; i < 4; ++i){
                    int gr = row0 + mrow + mt*16 + quad*4 + i;
                    if (gr < 360){
                        long long base = ((long long)z*360 + gr)*512;
                        #pragma unroll
                        for (int nt = 0; nt < 4; ++nt){
                            int gc = col0 + ncol + nt*16 + l16;
                            if constexpr (STORE == 0){
                                ((u16*)C)[base + gc] = f2bf(acc[mt][nt][i]);
                            } else {
                                ((float*)C)[base + gc] = fmaf(acc[mt][nt][i], scale, X[base + gc]);
                            }
                        }
                    }
                }
            }
            #pragma unroll
            for (int mt = 0; mt < 4; ++mt)
                #pragma unroll
                for (int nt = 0; nt < 4; ++nt)
                    acc[mt][nt] = (f4)0.0f;
            ++zi;
            kt = 0;
        } else {
            ++kt;
        }
        buf ^= 1;
    }
    #undef WSTAGE
}

// ---------------- MFMA block-MLP + softshrink ----------------
__global__ __launch_bounds__(256)
void mlp_k(const u16* __restrict__ xh, const u16* __restrict__ wts,
           const float* __restrict__ b1, const float* __restrict__ b2,
           u16* __restrict__ yout)
{
    __shared__ u16 sW0[64*72], sW1[64*72];
    __shared__ u16 sXh[64*72], sXn[64*72], s1k[64*72], s1n[64*72];
    __shared__ float sb[256];

    const int tid = threadIdx.x;
    const int wv = tid >> 6, l = tid & 63, lane16 = l & 15, quad = l >> 4;
    const int kb = blockIdx.y;
    const int p0 = blockIdx.x * 64;
    const int w16 = wv * 16;

    if (tid < 64){
        sb[tid]       = b1[kb*64 + tid];
        sb[64 + tid]  = b1[512 + kb*64 + tid];
        sb[128 + tid] = b2[kb*64 + tid];
        sb[192 + tid] = b2[512 + kb*64 + tid];
    }
    {
        const int r = tid >> 2, sg = (tid & 3) * 16;
        const u16* s0 = wts + kb*4096 + r*64 + sg;            // w1a_t
        const u16* s1 = wts + 32768 + kb*4096 + r*64 + sg;    // w1b_t
        *(uint4*)&sW0[r*72 + sg]     = *(const uint4*)s0;
        *(uint4*)&sW0[r*72 + sg + 8] = *(const uint4*)(s0 + 8);
        *(uint4*)&sW1[r*72 + sg]     = *(const uint4*)s1;
        *(uint4*)&sW1[r*72 + sg + 8] = *(const uint4*)(s1 + 8);

        int p = p0 + r; int pc = p <= 64799 ? p : 64799;
        int h = pc / 360; int v = pc - h * 360;
        int hn = (h == 0) ? 0 : (180 - h);
        int vn = (v == 0) ? 0 : (360 - v);
        long long bh = (long long)pc * 512 + kb*64 + sg;
        long long bn = (long long)(hn*360 + vn) * 512 + kb*64 + sg;
        *(uint4*)&sXh[r*72 + sg]     = *(const uint4*)&xh[bh];
        *(uint4*)&sXh[r*72 + sg + 8] = *(const uint4*)&xh[bh + 8];
        *(uint4*)&sXn[r*72 + sg]     = *(const uint4*)&xh[bn];
        *(uint4*)&sXn[r*72 + sg + 8] = *(const uint4*)&xh[bn + 8];
    }
    __syncthreads();

    // -------- layer 1 --------
    f4 aK[4], aN[4];
    #pragma unroll
    for (int nt = 0; nt < 4; ++nt){ aK[nt] = (f4)0.0f; aN[nt] = (f4)0.0f; }
    #pragma unroll
    for (int kq = 0; kq < 2; ++kq){
        short8 fxh = *(const short8*)&sXh[(w16 + lane16)*72 + kq*32 + quad*8];
        short8 fxn = *(const short8*)&sXn[(w16 + lane16)*72 + kq*32 + quad*8];
        #pragma unroll
        for (int nt = 0; nt < 4; ++nt){
            short8 wa = *(const short8*)&sW0[(nt*16 + lane16)*72 + kq*32 + quad*8];
            short8 wb = *(const short8*)&sW1[(nt*16 + lane16)*72 + kq*32 + quad*8];
            aK[nt] = __builtin_amdgcn_mfma_f32_16x16x32_bf16(fxh, wa, aK[nt], 0,0,0);
            aK[nt] = __builtin_amdgcn_mfma_f32_16x16x32_bf16(fxn, wb, aK[nt], 0,0,0);
            aN[nt] = __builtin_amdgcn_mfma_f32_16x16x32_bf16(fxn, wa, aN[nt], 0,0,0);
            aN[nt] = __builtin_amdgcn_mfma_f32_16x16x32_bf16(fxh, wb, aN[nt], 0,0,0);
        }
    }
    #pragma unroll
    for (int nt = 0; nt < 4; ++nt){
        int cc = nt*16 + lane16;
        #pragma unroll
        for (int i = 0; i < 4; ++i){
            int rr = w16 + quad*4 + i;
            float vk = fmaxf(aK[nt][i] + sb[cc], 0.f);
            float vn = fmaxf(aN[nt][i] + sb[64 + cc], 0.f);
            s1k[rr*72 + cc] = f2bf(vk);
            s1n[rr*72 + cc] = f2bf(vn);
        }
    }
    __syncthreads();

    // -------- swap weights to layer 2 --------
    {
        const int r = tid >> 2, sg = (tid & 3) * 16;
        const u16* s0 = wts + 65536 + kb*4096 + r*64 + sg;    // w2a_t
        const u16* s1 = wts + 98304 + kb*4096 + r*64 + sg;    // w2b_t
        *(uint4*)&sW0[r*72 + sg]     = *(const uint4*)s0;
        *(uint4*)&sW0[r*72 + sg + 8] = *(const uint4*)(s0 + 8);
        *(uint4*)&sW1[r*72 + sg]     = *(const uint4*)s1;
        *(uint4*)&sW1[r*72 + sg + 8] = *(const uint4*)(s1 + 8);
    }
    __syncthreads();

    // -------- layer 2a: o2k --------
    f4 k2[4];
    #pragma unroll
    for (int nt = 0; nt < 4; ++nt) k2[nt] = (f4)0.0f;
    #pragma unroll
    for (int kq = 0; kq < 2; ++kq){
        short8 a1k = *(const short8*)&s1k[(w16 + lane16)*72 + kq*32 + quad*8];
        short8 a1n = *(const short8*)&s1n[(w16 + lane16)*72 + kq*32 + quad*8];
        #pragma unroll
        for (int nt = 0; nt < 4; ++nt){
            short8 wa = *(const short8*)&sW0[(nt*16 + lane16)*72 + kq*32 + quad*8];
            short8 wb = *(const short8*)&sW1[(nt*16 + lane16)*72 + kq*32 + quad*8];
            k2[nt] = __builtin_amdgcn_mfma_f32_16x16x32_bf16(a1k, wa, k2[nt], 0,0,0);
            k2[nt] = __builtin_amdgcn_mfma_f32_16x16x32_bf16(a1n, wb, k2[nt], 0,0,0);
        }
    }
    #pragma unroll
    for (int nt = 0; nt < 4; ++nt){
        int cc = nt*16 + lane16;
        #pragma unroll
        for (int i = 0; i < 4; ++i){
            int rr = w16 + quad*4 + i;
            float v2 = k2[nt][i] + sb[128 + cc];
            k2[nt][i] = v2;                        // keep o2k (with bias) in regs
            sXh[rr*72 + cc] = f2bf(v2);            // reuse sXh as o2k A-operand
        }
    }
    __syncthreads();

    // -------- layer 2b: o2n (consumes o2k per source bug) + softshrink --------
    f4 n2[4];
    #pragma unroll
    for (int nt = 0; nt < 4; ++nt) n2[nt] = (f4)0.0f;
    #pragma unroll
    for (int kq = 0; kq < 2; ++kq){
        short8 a1n = *(const short8*)&s1n[(w16 + lane16)*72 + kq*32 + quad*8];
        short8 a2k = *(const short8*)&sXh[(w16 + lane16)*72 + kq*32 + quad*8];
        #pragma unroll
        for (int nt = 0; nt < 4; ++nt){
            short8 wa = *(const short8*)&sW0[(nt*16 + lane16)*72 + kq*32 + quad*8];
            short8 wb = *(const short8*)&sW1[(nt*16 + lane16)*72 + kq*32 + quad*8];
            n2[nt] = __builtin_amdgcn_mfma_f32_16x16x32_bf16(a1n, wa, n2[nt], 0,0,0);
            n2[nt] = __builtin_amdgcn_mfma_f32_16x16x32_bf16(a2k, wb, n2[nt], 0,0,0);
        }
    }
    #pragma unroll
    for (int nt = 0; nt < 4; ++nt){
        int cc = nt*16 + lane16;
        #pragma unroll
        for (int i = 0; i < 4; ++i){
            int rr = w16 + quad*4 + i;
            int p = p0 + rr;
            float y = k2[nt][i] + n2[nt][i] + sb[192 + cc];
            float ay = fabsf(y) - 0.01f;           // softshrink lambda
            float r0 = ay > 0.f ? (y > 0.f ? ay : -ay) : 0.f;
            if (p < 64800) yout[(long long)p * 512 + kb*64 + cc] = f2bf(r0);
        }
    }
}

// ---------------- launch ----------------
extern "C" void kernel_launch(void* const* d_in, const int* in_sizes, int n_in,
                              void* d_out, int out_size, void* d_ws, size_t ws_size,
                              hipStream_t stream) {
    const float* x  = (const float*)d_in[0];
    const float* w1 = (const float*)d_in[1];
    const float* b1 = (const float*)d_in[2];
    const float* w2 = (const float*)d_in[3];
    const float* b2 = (const float*)d_in[4];
    float* out = (float*)d_out;

    u16* ws   = (u16*)d_ws;
    u16* casC = ws;                        // 262144
    u16* casW = casC + 262144;             // 360*384 = 138240
    u16* wts  = casW + 138240;             // 131072
    u16* bufT = wts  + 131072;             // 33177600 + 64 pad (T1 / y)
    u16* bufP = bufT + 33177664;           // 33177600 + 64 pad (xbf / xh / Z)
    // total ws ~133.8 MB

    prep<<<1024, 256, 0, stream>>>(w1, w2, casC, casW, wts,
                                   bufT + 33177600, bufP + 33177600);
    cvt_k<<<16200, 256, 0, stream>>>(x, bufP);   // xbf -> bufP (dead until B overwrites)

    dim3 gBig(2028, 1, 1);    // 507 row-blocks x 4 col-blocks, XCD-swizzled in-kernel
    dim3 gWg(216, 1, 1);      // 3 bx x 2 by x 36 z-chunks (5 planes each)
    dim3 gM(1013, 8, 1);

    // A) T1[h][d][w] = (xbf . casC) transposed       (channel contraction)
    gemm_k<1,1><<<gBig, 256, 0, stream>>>(bufP, 512, 0, 64799,
                                          casC, 512, 0,
                                          bufT, 0, 64800, nullptr, 0.f, 16, 4);
    // B) xh[(h,v)][d] = sum_w casW[v][w] * T1[h][d][w]  (width contraction)
    wgemm_k<0><<<gWg, 512, 0, stream>>>(casW, bufT, bufP, nullptr, 0.f);
    // C) block-MLP + softshrink: xh -> y
    mlp_k<<<gM, 256, 0, stream>>>(bufP, wts, b1, b2, bufT);
    // D) Z[h][d][w] = (y . casC) transposed
    gemm_k<1,1><<<gBig, 256, 0, stream>>>(bufT, 512, 0, 64799,
                                          casC, 512, 0,
                                          bufP, 0, 64800, nullptr, 0.f, 16, 4);
    // E) out[(h,v)][d] = (sum_w casW[v][w] * Z[h][d][w]) / 184320 + x
    wgemm_k<2><<<gWg, 512, 0, stream>>>(casW, bufP, out, x, 1.0f/184320.0f);
}